// Round 10
// baseline (317.279 us; speedup 1.0000x reference)
//
#include <hip/hip_runtime.h>
#include <math.h>
#include <stdint.h>

#define NTOK 131072
#define DIM  256
#define KEMB 1024

typedef _Float16 f16x8 __attribute__((ext_vector_type(8)));
typedef float    f32x4 __attribute__((ext_vector_type(4)));

#define FLAG_CAP 65536
#define FLAG_THR 8u    // prefix units (>=0.0625 each) -> flags any gap < ~0.5

static __device__ __forceinline__ unsigned umin32(unsigned a, unsigned b){ return a<b?a:b; }
static __device__ __forceinline__ unsigned umax32(unsigned a, unsigned b){ return a>b?a:b; }

static __device__ __forceinline__ void gload_lds16(const void* g, void* l) {
    __builtin_amdgcn_global_load_lds(
        (const __attribute__((address_space(1))) unsigned int*)g,
        (__attribute__((address_space(3))) unsigned int*)l, 16, 0, 0);
}

static __device__ __forceinline__ void split_hl(const float4& f0, const float4& f1,
                                                f16x8& h, f16x8& l) {
    float v[8] = {f0.x, f0.y, f0.z, f0.w, f1.x, f1.y, f1.z, f1.w};
    #pragma unroll
    for (int e = 0; e < 8; ++e) {
        const _Float16 hi = (_Float16)v[e];
        h[e] = hi;
        l[e] = (_Float16)(v[e] - (float)hi);
    }
}

// ---------------- prep: norms, cst2, counters, UNSWIZZLED hi/lo fp16 codebook ----
// img layout: half index k*256 + p*8 holds emb[k][p*8 .. p*8+7].
__global__ __launch_bounds__(64) void prep_kernel(const float* __restrict__ emb,
                                                  float* __restrict__ eNorm,
                                                  float* __restrict__ cst2,
                                                  unsigned* __restrict__ counts,
                                                  unsigned* __restrict__ flagCnt,
                                                  _Float16* __restrict__ img_hi,
                                                  _Float16* __restrict__ img_lo) {
    const int k = blockIdx.x;
    const int lane = threadIdx.x;
    const float4 v = *reinterpret_cast<const float4*>(emb + (size_t)k * DIM + lane * 4);
    float s = v.x * v.x + v.y * v.y + v.z * v.z + v.w * v.w;
    #pragma unroll
    for (int m = 32; m; m >>= 1) s += __shfl_xor(s, m, 64);
    if (lane == 0) {
        eNorm[k] = s;
        cst2[k]  = s + 512.0f;       // d = cst2 - 2*dot > 0 always
        counts[k] = 0u;
        if (k == 0) *flagCnt = 0u;
    }
    if (lane < 32) {
        const int p = lane;
        const float4 f0 = *reinterpret_cast<const float4*>(emb + (size_t)k * DIM + p * 8);
        const float4 f1 = *reinterpret_cast<const float4*>(emb + (size_t)k * DIM + p * 8 + 4);
        f16x8 h, l;
        split_hl(f0, f1, h, l);
        *reinterpret_cast<f16x8*>(img_hi + (size_t)k * 256 + p * 8) = h;
        *reinterpret_cast<f16x8*>(img_lo + (size_t)k * 256 + p * 8) = l;
    }
}

// ---------------- main: barrier-free, LDS-free inner loop ----------------
// 4 waves x 64 tokens = 256 tokens/block, grid 512 (one resident generation).
// B-fragments read per-lane from the L2-resident fp16 codebook image; no staging.
__global__ __launch_bounds__(256, 2) void vq_main(const float* __restrict__ x,
                                                  const float* __restrict__ emb,
                                                  const _Float16* __restrict__ img,
                                                  const float* __restrict__ cst2,
                                                  int* __restrict__ idxArr,
                                                  unsigned* __restrict__ counts,
                                                  unsigned* __restrict__ flagCnt,
                                                  unsigned* __restrict__ flagList,
                                                  float* __restrict__ out) {
    __shared__ int idx_s[256];

    const int tid  = threadIdx.x;
    const int wv   = tid >> 6;
    const int lane = tid & 63;
    const int g    = lane >> 4;     // k-group 0..3
    const int c    = lane & 15;     // row/col within 16
    const int T0   = blockIdx.x * 256;
    const int T0w  = T0 + wv * 64;

    // A fragments: 4 row-blocks x 8 k-frags (compiler places in AGPRs)
    f16x8 a[4][8];
    #pragma unroll
    for (int i = 0; i < 4; ++i) {
        const float* xr = x + (size_t)(T0w + i * 16 + c) * DIM + g * 8;
        #pragma unroll
        for (int kk = 0; kk < 8; ++kk) {
            const float4 f0 = *reinterpret_cast<const float4*>(xr + kk * 32);
            const float4 f1 = *reinterpret_cast<const float4*>(xr + kk * 32 + 4);
            a[i][kk] = (f16x8){(_Float16)f0.x, (_Float16)f0.y, (_Float16)f0.z, (_Float16)f0.w,
                               (_Float16)f1.x, (_Float16)f1.y, (_Float16)f1.z, (_Float16)f1.w};
        }
    }

    unsigned m1[16], m2[16];
    #pragma unroll
    for (int t = 0; t < 16; ++t) { m1[t] = 0xFFFFFFFFu; m2[t] = 0xFFFFFFFFu; }

    // 64 chunks of 16 codewords; no barriers, no LDS — waves self-paced.
    #pragma unroll 2
    for (int ec = 0; ec < 64; ++ec) {
        const int col = ec * 16 + c;
        const float cst = cst2[col];

        f16x8 b[8];
        #pragma unroll
        for (int kk = 0; kk < 8; ++kk)
            b[kk] = *reinterpret_cast<const f16x8*>(
                img + (size_t)col * 256 + (kk * 4 + g) * 8);

        f32x4 acc[4];
        #pragma unroll
        for (int i = 0; i < 4; ++i) acc[i] = (f32x4){0.f, 0.f, 0.f, 0.f};

        #pragma unroll
        for (int kk = 0; kk < 8; ++kk)
            #pragma unroll
            for (int i = 0; i < 4; ++i)
                acc[i] = __builtin_amdgcn_mfma_f32_16x16x32_f16(a[i][kk], b[kk], acc[i], 0, 0, 0);

        // fold: key = (bits(d) & ~1023) | col  (d > 0 -> bits monotone in d)
        #pragma unroll
        for (int i = 0; i < 4; ++i)
            #pragma unroll
            for (int e = 0; e < 4; ++e) {
                const float    d   = fmaf(acc[i][e], -2.0f, cst);
                const unsigned key = (__builtin_bit_cast(unsigned, d) & 0xFFFFFC00u) | (unsigned)col;
                const int t = i * 4 + e;
                m2[t] = umin32(m2[t], umax32(key, m1[t]));
                m1[t] = umin32(m1[t], key);
            }
    }

    // reduce across the 16 c-lanes (tokens in rows, cols across lanes)
    #pragma unroll
    for (int off = 1; off < 16; off <<= 1) {
        #pragma unroll
        for (int t = 0; t < 16; ++t) {
            const unsigned o1 = __shfl_xor(m1[t], off, 64);
            const unsigned o2 = __shfl_xor(m2[t], off, 64);
            const unsigned nm2 = umin32(umin32(m2[t], o2), umax32(m1[t], o1));
            m1[t] = umin32(m1[t], o1);
            m2[t] = nm2;
        }
    }

    if (c == 0) {
        #pragma unroll
        for (int t = 0; t < 16; ++t) {
            const int i   = t >> 2;            // row-block
            const int e   = t & 3;
            const int row = i * 16 + g * 4 + e;   // within wave's 64 tokens
            const int idx = (int)(m1[t] & 1023u);
            idx_s[wv * 64 + row] = idx;
            idxArr[T0w + row] = idx;
            atomicAdd(&counts[idx], 1u);
            if (((m2[t] >> 10) - (m1[t] >> 10)) < FLAG_THR) {
                const unsigned pos = atomicAdd(flagCnt, 1u);
                if (pos < FLAG_CAP) flagList[pos] = (unsigned)(T0w + row);
            }
        }
    }
    __syncthreads();

    // fused gather: out[token] = emb[idx]  (256 rows x 1KB)
    #pragma unroll 4
    for (int s = 0; s < 64; ++s) {
        const int fi  = s * 256 + tid;
        const int row = fi >> 6;
        const int q4  = fi & 63;
        const int em  = idx_s[row];
        *reinterpret_cast<float4*>(out + (size_t)(T0 + row) * DIM + q4 * 4) =
            *reinterpret_cast<const float4*>(emb + (size_t)em * DIM + q4 * 4);
    }
}

// ---------------- fixup stage A: hi/lo-split 3-MFMA full rescan -> refined top-2 ----
__global__ __launch_bounds__(256) void fixup_refine(const float* __restrict__ x,
                                                    const _Float16* __restrict__ img_hi,
                                                    const _Float16* __restrict__ img_lo,
                                                    const float* __restrict__ cst2,
                                                    const unsigned* __restrict__ flagCnt,
                                                    const unsigned* __restrict__ flagList,
                                                    uint2* __restrict__ refTop) {
    __shared__ _Float16 Bh[16384];
    __shared__ _Float16 Bl[16384];
    __shared__ float cst_s[1024];

    const unsigned nf = umin32(*flagCnt, (unsigned)FLAG_CAP);
    if (blockIdx.x * 64u >= nf) return;

    const int tid  = threadIdx.x;
    const int wv   = tid >> 6;
    const int lane = tid & 63;
    const int g    = lane >> 4;
    const int c    = lane & 15;
    const unsigned base = (blockIdx.x * 4u + (unsigned)wv) * 16u;

    *reinterpret_cast<float4*>(&cst_s[tid * 4]) =
        *reinterpret_cast<const float4*>(&cst2[tid * 4]);

    const unsigned myTok = flagList[(base + c) < nf ? (base + c) : 0];
    f16x8 ah[8], al[8];
    {
        const float* xr = x + (size_t)myTok * DIM + g * 8;
        #pragma unroll
        for (int kk = 0; kk < 8; ++kk) {
            const float4 f0 = *reinterpret_cast<const float4*>(xr + kk * 32);
            const float4 f1 = *reinterpret_cast<const float4*>(xr + kk * 32 + 4);
            split_hl(f0, f1, ah[kk], al[kk]);
        }
    }

    unsigned m1[4], m2[4];
    #pragma unroll
    for (int e = 0; e < 4; ++e) { m1[e] = 0xFFFFFFFFu; m2[e] = 0xFFFFFFFFu; }

    for (int ec = 0; ec < 16; ++ec) {
        __syncthreads();
        #pragma unroll
        for (int i = 0; i < 8; ++i) {
            gload_lds16((const char*)img_hi + ec * 32768 + (i * 256 + tid) * 16,
                        (char*)&Bh[0] + i * 4096 + wv * 1024);
            gload_lds16((const char*)img_lo + ec * 32768 + (i * 256 + tid) * 16,
                        (char*)&Bl[0] + i * 4096 + wv * 1024);
        }
        __syncthreads();

        f32x4 acc[4];
        #pragma unroll
        for (int j = 0; j < 4; ++j) acc[j] = (f32x4){0.f, 0.f, 0.f, 0.f};

        #pragma unroll
        for (int kk = 0; kk < 8; ++kk) {
            #pragma unroll
            for (int j = 0; j < 4; ++j) {
                const int row = j * 16 + c;
                const int off = row * 256 + (kk * 4 + g) * 8;   // unswizzled
                const f16x8 bh = *reinterpret_cast<const f16x8*>(&Bh[off]);
                const f16x8 bl = *reinterpret_cast<const f16x8*>(&Bl[off]);
                acc[j] = __builtin_amdgcn_mfma_f32_16x16x32_f16(ah[kk], bh, acc[j], 0, 0, 0);
                acc[j] = __builtin_amdgcn_mfma_f32_16x16x32_f16(ah[kk], bl, acc[j], 0, 0, 0);
                acc[j] = __builtin_amdgcn_mfma_f32_16x16x32_f16(al[kk], bh, acc[j], 0, 0, 0);
            }
        }

        #pragma unroll
        for (int j = 0; j < 4; ++j) {
            const int   col = ec * 64 + j * 16 + c;
            const float cst = cst_s[col];
            #pragma unroll
            for (int e = 0; e < 4; ++e) {
                const float    d   = fmaf(acc[j][e], -2.0f, cst);
                const unsigned key = (__builtin_bit_cast(unsigned, d) & 0xFFFFFC00u) | (unsigned)col;
                m2[e] = umin32(m2[e], umax32(key, m1[e]));
                m1[e] = umin32(m1[e], key);
            }
        }
    }

    #pragma unroll
    for (int off = 1; off < 16; off <<= 1) {
        #pragma unroll
        for (int e = 0; e < 4; ++e) {
            const unsigned o1 = __shfl_xor(m1[e], off, 64);
            const unsigned o2 = __shfl_xor(m2[e], off, 64);
            const unsigned nm2 = umin32(umin32(m2[e], o2), umax32(m1[e], o1));
            m1[e] = umin32(m1[e], o1);
            m2[e] = nm2;
        }
    }

    if (c == 0) {
        #pragma unroll
        for (int e = 0; e < 4; ++e) {
            const unsigned pos = base + (unsigned)(g * 4 + e);
            if (pos < nf) refTop[pos] = make_uint2(m1[e], m2[e]);
        }
    }
}

// ---------------- fixup stage B: exact fp32 compare of refined top-2, patch ----------
__global__ __launch_bounds__(256) void fixup_exact(const float* __restrict__ x,
                                                   const float* __restrict__ emb,
                                                   const float* __restrict__ eNorm,
                                                   const unsigned* __restrict__ flagCnt,
                                                   const unsigned* __restrict__ flagList,
                                                   const uint2* __restrict__ refTop,
                                                   int* __restrict__ idxArr,
                                                   unsigned* __restrict__ counts,
                                                   float* __restrict__ out) {
    const unsigned nf = umin32(*flagCnt, (unsigned)FLAG_CAP);
    const int tid  = threadIdx.x;
    const int wv   = tid >> 6;
    const int lane = tid & 63;

    for (unsigned pos = blockIdx.x * 4u + (unsigned)wv; pos < nf; pos += gridDim.x * 4u) {
        const unsigned tok = flagList[pos];
        const uint2 tk = refTop[pos];
        const int e1 = (int)(tk.x & 1023u);
        const int e2 = (int)(tk.y & 1023u);

        const float4 xv = *reinterpret_cast<const float4*>(x   + (size_t)tok * DIM + lane * 4);
        const float4 v1 = *reinterpret_cast<const float4*>(emb + (size_t)e1  * DIM + lane * 4);
        const float4 v2 = *reinterpret_cast<const float4*>(emb + (size_t)e2  * DIM + lane * 4);
        float p1 = xv.x * v1.x + xv.y * v1.y + xv.z * v1.z + xv.w * v1.w;
        float p2 = xv.x * v2.x + xv.y * v2.y + xv.z * v2.z + xv.w * v2.w;
        #pragma unroll
        for (int off = 1; off < 64; off <<= 1) {
            p1 += __shfl_xor(p1, off, 64);
            p2 += __shfl_xor(p2, off, 64);
        }
        const float d1 = eNorm[e1] - 2.0f * p1;
        const float d2 = eNorm[e2] - 2.0f * p2;
        const bool pick2 = (d2 < d1) || (d2 == d1 && e2 < e1);
        const int  ni   = pick2 ? e2 : e1;
        const int  old  = idxArr[tok];
        if (ni != old) {
            if (lane == 0) {
                idxArr[tok] = ni;
                atomicSub(&counts[old], 1u);
                atomicAdd(&counts[ni], 1u);
            }
            const float4 nv = pick2 ? v2 : v1;
            *reinterpret_cast<float4*>(out + (size_t)tok * DIM + lane * 4) = nv;
        }
    }
}

// ---------------- perplexity ----------------
__global__ __launch_bounds__(256) void perp_kernel(const unsigned* __restrict__ counts,
                                                   float* __restrict__ out_perp) {
    __shared__ float red[256];
    const int tid = threadIdx.x;
    float s = 0.0f;
    for (int i = tid; i < KEMB; i += 256) {
        const float p = (float)counts[i] / (float)NTOK;
        s += p * logf(p + 1e-10f);
    }
    red[tid] = s;
    __syncthreads();
    for (int off = 128; off; off >>= 1) {
        if (tid < off) red[tid] += red[tid + off];
        __syncthreads();
    }
    if (tid == 0) *out_perp = expf(-red[0]);
}

extern "C" void kernel_launch(void* const* d_in, const int* in_sizes, int n_in,
                              void* d_out, int out_size, void* d_ws, size_t ws_size,
                              hipStream_t stream) {
    (void)in_sizes; (void)n_in; (void)out_size; (void)ws_size;
    const float* x   = (const float*)d_in[0];
    const float* emb = (const float*)d_in[1];
    float* out = (float*)d_out;

    char* ws = (char*)d_ws;
    float*     eNorm    = (float*)(ws);                          // 4KB
    float*     cst2     = (float*)(ws + 4096);                   // 4KB
    unsigned*  counts   = (unsigned*)(ws + 8192);                // 4KB
    unsigned*  flagCnt  = (unsigned*)(ws + 12288);               // 4KB
    unsigned*  flagList = (unsigned*)(ws + 16384);               // 256KB
    int*       idxArr   = (int*)(ws + 278528);                   // 512KB
    _Float16*  img_hi   = (_Float16*)(ws + 802816);              // 512KB
    _Float16*  img_lo   = (_Float16*)(ws + 1327104);             // 512KB
    uint2*     refTop   = (uint2*)(ws + 1851392);                // 512KB

    prep_kernel<<<KEMB, 64, 0, stream>>>(emb, eNorm, cst2, counts, flagCnt, img_hi, img_lo);
    vq_main<<<NTOK / 256, 256, 0, stream>>>(x, emb, img_hi, cst2, idxArr, counts,
                                            flagCnt, flagList, out);
    fixup_refine<<<1024, 256, 0, stream>>>(x, img_hi, img_lo, cst2, flagCnt, flagList, refTop);
    fixup_exact<<<2048, 256, 0, stream>>>(x, emb, eNorm, flagCnt, flagList, refTop,
                                          idxArr, counts, out);
    perp_kernel<<<1, 256, 0, stream>>>(counts, out + (size_t)NTOK * DIM);
}

// Round 11
// 206.467 us; speedup vs baseline: 1.5367x; 1.5367x over previous
//
#include <hip/hip_runtime.h>
#include <math.h>
#include <stdint.h>

#define NTOK 131072
#define DIM  256
#define KEMB 1024

typedef _Float16 f16x8 __attribute__((ext_vector_type(8)));
typedef float    f32x4 __attribute__((ext_vector_type(4)));

#define FLAG_CAP 65536
#define FLAG_THR 8u    // prefix units (>=0.0625 each) -> flags any gap < ~0.5

static __device__ __forceinline__ unsigned umin32(unsigned a, unsigned b){ return a<b?a:b; }
static __device__ __forceinline__ unsigned umax32(unsigned a, unsigned b){ return a>b?a:b; }

static __device__ __forceinline__ void gload_lds16(const void* g, void* l) {
    __builtin_amdgcn_global_load_lds(
        (const __attribute__((address_space(1))) unsigned int*)g,
        (__attribute__((address_space(3))) unsigned int*)l, 16, 0, 0);
}

static __device__ __forceinline__ void split_hl(const float4& f0, const float4& f1,
                                                f16x8& h, f16x8& l) {
    float v[8] = {f0.x, f0.y, f0.z, f0.w, f1.x, f1.y, f1.z, f1.w};
    #pragma unroll
    for (int e = 0; e < 8; ++e) {
        const _Float16 hi = (_Float16)v[e];
        h[e] = hi;
        l[e] = (_Float16)(v[e] - (float)hi);
    }
}

// ---------------- prep: norms, cst2, counters, SWIZZLED hi/lo fp16 codebook ----
// img layout: half idx k*256 + p*8 holds emb[k][(p^(k&7))*8 .. +7] (16B-slot XOR swizzle).
__global__ __launch_bounds__(64) void prep_kernel(const float* __restrict__ emb,
                                                  float* __restrict__ eNorm,
                                                  float* __restrict__ cst2,
                                                  unsigned* __restrict__ counts,
                                                  unsigned* __restrict__ flagCnt,
                                                  _Float16* __restrict__ img_hi,
                                                  _Float16* __restrict__ img_lo) {
    const int k = blockIdx.x;
    const int lane = threadIdx.x;
    const float4 v = *reinterpret_cast<const float4*>(emb + (size_t)k * DIM + lane * 4);
    float s = v.x * v.x + v.y * v.y + v.z * v.z + v.w * v.w;
    #pragma unroll
    for (int m = 32; m; m >>= 1) s += __shfl_xor(s, m, 64);
    if (lane == 0) {
        eNorm[k] = s;
        cst2[k]  = s + 512.0f;       // d = cst2 - 2*dot > 0 always
        counts[k] = 0u;
        if (k == 0) *flagCnt = 0u;
    }
    if (lane < 32) {
        const int p = lane;
        const int sl = p ^ (k & 7);
        const float4 f0 = *reinterpret_cast<const float4*>(emb + (size_t)k * DIM + sl * 8);
        const float4 f1 = *reinterpret_cast<const float4*>(emb + (size_t)k * DIM + sl * 8 + 4);
        f16x8 h, l;
        split_hl(f0, f1, h, l);
        *reinterpret_cast<f16x8*>(img_hi + (size_t)k * 256 + p * 8) = h;
        *reinterpret_cast<f16x8*>(img_lo + (size_t)k * 256 + p * 8) = l;
    }
}

// ---------------- main: wave-private double-buffered pipeline, no main-loop barriers --
// 4 waves x 64 tokens = 256 tokens/block, grid 512. Each wave prefetches its own
// 16-row (8KB) codebook chunk via global_load_lds and waits with counted vmcnt only.
__global__ __launch_bounds__(256, 2) void vq_main(const float* __restrict__ x,
                                                  const float* __restrict__ emb,
                                                  const _Float16* __restrict__ img,
                                                  const float* __restrict__ cst2,
                                                  int* __restrict__ idxArr,
                                                  unsigned* __restrict__ counts,
                                                  unsigned* __restrict__ flagCnt,
                                                  unsigned* __restrict__ flagList,
                                                  float* __restrict__ out) {
    __shared__ char Bsh[4][2][8192];   // per-wave double buffers (64KB)
    __shared__ float cst_s[1024];
    __shared__ int idx_s[256];

    const int tid  = threadIdx.x;
    const int wv   = tid >> 6;
    const int lane = tid & 63;
    const int g    = lane >> 4;     // k-group 0..3
    const int c    = lane & 15;     // row/col within 16
    const int T0   = blockIdx.x * 256;
    const int T0w  = T0 + wv * 64;

    char* const ldsbase = &Bsh[wv][0][0];

    // stage cst2 into LDS once
    *reinterpret_cast<float4*>(&cst_s[tid * 4]) =
        *reinterpret_cast<const float4*>(&cst2[tid * 4]);

    // issue chunk 0 into buf0 (8 x 1KB per wave, linear copy of swizzled image)
    {
        const char* src = (const char*)img + lane * 16;
        #pragma unroll
        for (int i = 0; i < 8; ++i)
            gload_lds16(src + i * 1024, ldsbase + i * 1024);
    }

    // A fragments: 4 row-blocks x 8 k-frags (AGPR-backed)
    f16x8 a[4][8];
    #pragma unroll
    for (int i = 0; i < 4; ++i) {
        const float* xr = x + (size_t)(T0w + i * 16 + c) * DIM + g * 8;
        #pragma unroll
        for (int kk = 0; kk < 8; ++kk) {
            const float4 f0 = *reinterpret_cast<const float4*>(xr + kk * 32);
            const float4 f1 = *reinterpret_cast<const float4*>(xr + kk * 32 + 4);
            a[i][kk] = (f16x8){(_Float16)f0.x, (_Float16)f0.y, (_Float16)f0.z, (_Float16)f0.w,
                               (_Float16)f1.x, (_Float16)f1.y, (_Float16)f1.z, (_Float16)f1.w};
        }
    }

    unsigned m1[16], m2[16];
    #pragma unroll
    for (int t = 0; t < 16; ++t) { m1[t] = 0xFFFFFFFFu; m2[t] = 0xFFFFFFFFu; }

    __syncthreads();   // cst_s visible (also drains chunk-0 loads)

#define ISSUE(NXT, ECN) do {                                                   \
        const char* _src = (const char*)img + (size_t)(ECN) * 8192 + lane * 16;\
        char* _dst = ldsbase + (NXT) * 8192;                                   \
        _Pragma("unroll")                                                      \
        for (int _i = 0; _i < 8; ++_i)                                         \
            gload_lds16(_src + _i * 1024, _dst + _i * 1024);                   \
    } while (0)

#define COMPUTE(CUR, EC) do {                                                  \
        const _Float16* _B = (const _Float16*)(ldsbase + (CUR) * 8192);        \
        const int   _col = (EC) * 16 + c;                                      \
        const float _cst = cst_s[_col];                                        \
        f32x4 _acc[4];                                                         \
        _Pragma("unroll")                                                      \
        for (int _i = 0; _i < 4; ++_i) _acc[_i] = (f32x4){0.f, 0.f, 0.f, 0.f}; \
        __builtin_amdgcn_s_setprio(1);                                         \
        _Pragma("unroll")                                                      \
        for (int _kk = 0; _kk < 8; ++_kk) {                                    \
            const f16x8 _b = *reinterpret_cast<const f16x8*>(                  \
                _B + c * 256 + (((_kk * 4 + g) ^ (c & 7)) << 3));              \
            _Pragma("unroll")                                                  \
            for (int _i = 0; _i < 4; ++_i)                                     \
                _acc[_i] = __builtin_amdgcn_mfma_f32_16x16x32_f16(             \
                    a[_i][_kk], _b, _acc[_i], 0, 0, 0);                        \
        }                                                                      \
        __builtin_amdgcn_s_setprio(0);                                         \
        _Pragma("unroll")                                                      \
        for (int _i = 0; _i < 4; ++_i)                                         \
            _Pragma("unroll")                                                  \
            for (int _e = 0; _e < 4; ++_e) {                                   \
                const float    _d = fmaf(_acc[_i][_e], -2.0f, _cst);           \
                const unsigned _k = (__builtin_bit_cast(unsigned, _d)          \
                                     & 0xFFFFFC00u) | (unsigned)_col;          \
                const int _t = _i * 4 + _e;                                    \
                m2[_t] = umin32(m2[_t], umax32(_k, m1[_t]));                   \
                m1[_t] = umin32(m1[_t], _k);                                   \
            }                                                                  \
    } while (0)

    for (int ec2 = 0; ec2 < 32; ++ec2) {
        const int ec0 = ec2 * 2;
        const int ec1 = ec0 + 1;

        ISSUE(1, ec0 + 1);
        asm volatile("s_waitcnt vmcnt(8)" ::: "memory");
        __builtin_amdgcn_sched_barrier(0);
        COMPUTE(0, ec0);

        if (ec1 < 63) {
            ISSUE(0, ec1 + 1);
            asm volatile("s_waitcnt vmcnt(8)" ::: "memory");
        } else {
            asm volatile("s_waitcnt vmcnt(0)" ::: "memory");
        }
        __builtin_amdgcn_sched_barrier(0);
        COMPUTE(1, ec1);
    }
#undef ISSUE
#undef COMPUTE

    // reduce across the 16 c-lanes (tokens in rows, cols across lanes)
    #pragma unroll
    for (int off = 1; off < 16; off <<= 1) {
        #pragma unroll
        for (int t = 0; t < 16; ++t) {
            const unsigned o1 = __shfl_xor(m1[t], off, 64);
            const unsigned o2 = __shfl_xor(m2[t], off, 64);
            const unsigned nm2 = umin32(umin32(m2[t], o2), umax32(m1[t], o1));
            m1[t] = umin32(m1[t], o1);
            m2[t] = nm2;
        }
    }

    if (c == 0) {
        #pragma unroll
        for (int t = 0; t < 16; ++t) {
            const int i   = t >> 2;
            const int e   = t & 3;
            const int row = i * 16 + g * 4 + e;   // within wave's 64 tokens
            const int idx = (int)(m1[t] & 1023u);
            idx_s[wv * 64 + row] = idx;
            idxArr[T0w + row] = idx;
            atomicAdd(&counts[idx], 1u);
            if (((m2[t] >> 10) - (m1[t] >> 10)) < FLAG_THR) {
                const unsigned pos = atomicAdd(flagCnt, 1u);
                if (pos < FLAG_CAP) flagList[pos] = (unsigned)(T0w + row);
            }
        }
    }
    __syncthreads();

    // fused gather: out[token] = emb[idx]  (256 rows x 1KB)
    #pragma unroll 4
    for (int s = 0; s < 64; ++s) {
        const int fi  = s * 256 + tid;
        const int row = fi >> 6;
        const int q4  = fi & 63;
        const int em  = idx_s[row];
        *reinterpret_cast<float4*>(out + (size_t)(T0 + row) * DIM + q4 * 4) =
            *reinterpret_cast<const float4*>(emb + (size_t)em * DIM + q4 * 4);
    }
}

// ---------------- fixup stage A: hi/lo-split 3-MFMA full rescan -> refined top-2 ----
__global__ __launch_bounds__(256) void fixup_refine(const float* __restrict__ x,
                                                    const _Float16* __restrict__ img_hi,
                                                    const _Float16* __restrict__ img_lo,
                                                    const float* __restrict__ cst2,
                                                    const unsigned* __restrict__ flagCnt,
                                                    const unsigned* __restrict__ flagList,
                                                    uint2* __restrict__ refTop) {
    __shared__ _Float16 Bh[16384];
    __shared__ _Float16 Bl[16384];
    __shared__ float cst_s[1024];

    const unsigned nf = umin32(*flagCnt, (unsigned)FLAG_CAP);
    if (blockIdx.x * 64u >= nf) return;

    const int tid  = threadIdx.x;
    const int wv   = tid >> 6;
    const int lane = tid & 63;
    const int g    = lane >> 4;
    const int c    = lane & 15;
    const unsigned base = (blockIdx.x * 4u + (unsigned)wv) * 16u;

    *reinterpret_cast<float4*>(&cst_s[tid * 4]) =
        *reinterpret_cast<const float4*>(&cst2[tid * 4]);

    const unsigned myTok = flagList[(base + c) < nf ? (base + c) : 0];
    f16x8 ah[8], al[8];
    {
        const float* xr = x + (size_t)myTok * DIM + g * 8;
        #pragma unroll
        for (int kk = 0; kk < 8; ++kk) {
            const float4 f0 = *reinterpret_cast<const float4*>(xr + kk * 32);
            const float4 f1 = *reinterpret_cast<const float4*>(xr + kk * 32 + 4);
            split_hl(f0, f1, ah[kk], al[kk]);
        }
    }

    unsigned m1[4], m2[4];
    #pragma unroll
    for (int e = 0; e < 4; ++e) { m1[e] = 0xFFFFFFFFu; m2[e] = 0xFFFFFFFFu; }

    for (int ec = 0; ec < 16; ++ec) {
        __syncthreads();
        #pragma unroll
        for (int i = 0; i < 8; ++i) {
            gload_lds16((const char*)img_hi + ec * 32768 + (i * 256 + tid) * 16,
                        (char*)&Bh[0] + i * 4096 + wv * 1024);
            gload_lds16((const char*)img_lo + ec * 32768 + (i * 256 + tid) * 16,
                        (char*)&Bl[0] + i * 4096 + wv * 1024);
        }
        __syncthreads();

        f32x4 acc[4];
        #pragma unroll
        for (int j = 0; j < 4; ++j) acc[j] = (f32x4){0.f, 0.f, 0.f, 0.f};

        #pragma unroll
        for (int kk = 0; kk < 8; ++kk) {
            #pragma unroll
            for (int j = 0; j < 4; ++j) {
                const int row = j * 16 + c;
                const int off = row * 256 + (((kk * 4 + g) ^ (row & 7)) << 3);  // swizzled
                const f16x8 bh = *reinterpret_cast<const f16x8*>(&Bh[off]);
                const f16x8 bl = *reinterpret_cast<const f16x8*>(&Bl[off]);
                acc[j] = __builtin_amdgcn_mfma_f32_16x16x32_f16(ah[kk], bh, acc[j], 0, 0, 0);
                acc[j] = __builtin_amdgcn_mfma_f32_16x16x32_f16(ah[kk], bl, acc[j], 0, 0, 0);
                acc[j] = __builtin_amdgcn_mfma_f32_16x16x32_f16(al[kk], bh, acc[j], 0, 0, 0);
            }
        }

        #pragma unroll
        for (int j = 0; j < 4; ++j) {
            const int   col = ec * 64 + j * 16 + c;
            const float cst = cst_s[col];
            #pragma unroll
            for (int e = 0; e < 4; ++e) {
                const float    d   = fmaf(acc[j][e], -2.0f, cst);
                const unsigned key = (__builtin_bit_cast(unsigned, d) & 0xFFFFFC00u) | (unsigned)col;
                m2[e] = umin32(m2[e], umax32(key, m1[e]));
                m1[e] = umin32(m1[e], key);
            }
        }
    }

    #pragma unroll
    for (int off = 1; off < 16; off <<= 1) {
        #pragma unroll
        for (int e = 0; e < 4; ++e) {
            const unsigned o1 = __shfl_xor(m1[e], off, 64);
            const unsigned o2 = __shfl_xor(m2[e], off, 64);
            const unsigned nm2 = umin32(umin32(m2[e], o2), umax32(m1[e], o1));
            m1[e] = umin32(m1[e], o1);
            m2[e] = nm2;
        }
    }

    if (c == 0) {
        #pragma unroll
        for (int e = 0; e < 4; ++e) {
            const unsigned pos = base + (unsigned)(g * 4 + e);
            if (pos < nf) refTop[pos] = make_uint2(m1[e], m2[e]);
        }
    }
}

// ---------------- fixup stage B: exact fp32 compare of refined top-2, patch ----------
__global__ __launch_bounds__(256) void fixup_exact(const float* __restrict__ x,
                                                   const float* __restrict__ emb,
                                                   const float* __restrict__ eNorm,
                                                   const unsigned* __restrict__ flagCnt,
                                                   const unsigned* __restrict__ flagList,
                                                   const uint2* __restrict__ refTop,
                                                   int* __restrict__ idxArr,
                                                   unsigned* __restrict__ counts,
                                                   float* __restrict__ out) {
    const unsigned nf = umin32(*flagCnt, (unsigned)FLAG_CAP);
    const int tid  = threadIdx.x;
    const int wv   = tid >> 6;
    const int lane = tid & 63;

    for (unsigned pos = blockIdx.x * 4u + (unsigned)wv; pos < nf; pos += gridDim.x * 4u) {
        const unsigned tok = flagList[pos];
        const uint2 tk = refTop[pos];
        const int e1 = (int)(tk.x & 1023u);
        const int e2 = (int)(tk.y & 1023u);

        const float4 xv = *reinterpret_cast<const float4*>(x   + (size_t)tok * DIM + lane * 4);
        const float4 v1 = *reinterpret_cast<const float4*>(emb + (size_t)e1  * DIM + lane * 4);
        const float4 v2 = *reinterpret_cast<const float4*>(emb + (size_t)e2  * DIM + lane * 4);
        float p1 = xv.x * v1.x + xv.y * v1.y + xv.z * v1.z + xv.w * v1.w;
        float p2 = xv.x * v2.x + xv.y * v2.y + xv.z * v2.z + xv.w * v2.w;
        #pragma unroll
        for (int off = 1; off < 64; off <<= 1) {
            p1 += __shfl_xor(p1, off, 64);
            p2 += __shfl_xor(p2, off, 64);
        }
        const float d1 = eNorm[e1] - 2.0f * p1;
        const float d2 = eNorm[e2] - 2.0f * p2;
        const bool pick2 = (d2 < d1) || (d2 == d1 && e2 < e1);
        const int  ni   = pick2 ? e2 : e1;
        const int  old  = idxArr[tok];
        if (ni != old) {
            if (lane == 0) {
                idxArr[tok] = ni;
                atomicSub(&counts[old], 1u);
                atomicAdd(&counts[ni], 1u);
            }
            const float4 nv = pick2 ? v2 : v1;
            *reinterpret_cast<float4*>(out + (size_t)tok * DIM + lane * 4) = nv;
        }
    }
}

// ---------------- perplexity ----------------
__global__ __launch_bounds__(256) void perp_kernel(const unsigned* __restrict__ counts,
                                                   float* __restrict__ out_perp) {
    __shared__ float red[256];
    const int tid = threadIdx.x;
    float s = 0.0f;
    for (int i = tid; i < KEMB; i += 256) {
        const float p = (float)counts[i] / (float)NTOK;
        s += p * logf(p + 1e-10f);
    }
    red[tid] = s;
    __syncthreads();
    for (int off = 128; off; off >>= 1) {
        if (tid < off) red[tid] += red[tid + off];
        __syncthreads();
    }
    if (tid == 0) *out_perp = expf(-red[0]);
}

extern "C" void kernel_launch(void* const* d_in, const int* in_sizes, int n_in,
                              void* d_out, int out_size, void* d_ws, size_t ws_size,
                              hipStream_t stream) {
    (void)in_sizes; (void)n_in; (void)out_size; (void)ws_size;
    const float* x   = (const float*)d_in[0];
    const float* emb = (const float*)d_in[1];
    float* out = (float*)d_out;

    char* ws = (char*)d_ws;
    float*     eNorm    = (float*)(ws);                          // 4KB
    float*     cst2     = (float*)(ws + 4096);                   // 4KB
    unsigned*  counts   = (unsigned*)(ws + 8192);                // 4KB
    unsigned*  flagCnt  = (unsigned*)(ws + 12288);               // 4KB
    unsigned*  flagList = (unsigned*)(ws + 16384);               // 256KB
    int*       idxArr   = (int*)(ws + 278528);                   // 512KB
    _Float16*  img_hi   = (_Float16*)(ws + 802816);              // 512KB
    _Float16*  img_lo   = (_Float16*)(ws + 1327104);             // 512KB
    uint2*     refTop   = (uint2*)(ws + 1851392);                // 512KB

    prep_kernel<<<KEMB, 64, 0, stream>>>(emb, eNorm, cst2, counts, flagCnt, img_hi, img_lo);
    vq_main<<<NTOK / 256, 256, 0, stream>>>(x, emb, img_hi, cst2, idxArr, counts,
                                            flagCnt, flagList, out);
    fixup_refine<<<1024, 256, 0, stream>>>(x, img_hi, img_lo, cst2, flagCnt, flagList, refTop);
    fixup_exact<<<2048, 256, 0, stream>>>(x, emb, eNorm, flagCnt, flagList, refTop,
                                          idxArr, counts, out);
    perp_kernel<<<1, 256, 0, stream>>>(counts, out + (size_t)NTOK * DIM);
}